// Round 3
// baseline (154.363 us; speedup 1.0000x reference)
//
#include <hip/hip_runtime.h>

#define NN 4096
#define MTOT 9
#define CH 128

// -------- Wigner-3j / TP constants (verified correct in R1/R2 passes) ----
#define S3f 0.57735026918962576f   // 1/sqrt(3)
#define S2f 0.70710678118654752f   // 1/sqrt(2)
#define CUf 0.54772255750516611f   // sqrt(3/10)
#define CVf 0.31622776601683794f   // sqrt(1/10)
#define CWf 0.63245553203367587f   // 2/sqrt(10)
#define CAf 0.40824829046386302f   // 1/sqrt(6)
#define CA2f 0.81649658092772603f  // 2/sqrt(6)
#define YSf ((float)(2.04665350914 * 0.48860251190291992))

typedef __attribute__((ext_vector_type(8))) short short8;
typedef __attribute__((ext_vector_type(4))) float f32x4;
typedef __attribute__((ext_vector_type(2))) float f32x2;

__device__ __forceinline__ unsigned short f2b(float f) {
  unsigned u = __builtin_bit_cast(unsigned, f);
  u += 0x7FFFu + ((u >> 16) & 1u);           // RNE
  return (unsigned short)(u >> 16);
}

// ---------------- so3_linear via MFMA 16x16x32 bf16 (unchanged from R2) ----
template <int XBF, int YBF, int NORM>
__global__ __launch_bounds__(256) void so3lin_mfma(
    const void* __restrict__ Xv, const float* __restrict__ W,
    const float* __restrict__ bias, void* __restrict__ Yv)
{
  __shared__ unsigned short Bs[16384];   // 32 KB swizzled bf16 W_l
  const int bid = blockIdx.x;
  int l, blk0, m0, nm;
  if (bid < 64)       { l = 0; blk0 = bid;       m0 = 0; nm = 1; }
  else if (bid < 256) { l = 1; blk0 = bid - 64;  m0 = 1; nm = 3; }
  else                { l = 2; blk0 = bid - 256; m0 = 4; nm = 5; }
  const float* Wl = W + l * CH * CH;
  const int t = threadIdx.x;

  #pragma unroll
  for (int i = 0; i < 16; ++i) {
    int idx4 = i * 256 + t;
    float4 v = ((const float4*)Wl)[idx4];
    int k = idx4 >> 5;
    int n = (idx4 & 31) * 4;
    int base = (((n >> 4) * 16 + (k >> 3)) * 16 + (n & 15)) * 8 + (k & 7);
    Bs[base]      = f2b(v.x);
    Bs[base + 8]  = f2b(v.y);
    Bs[base + 16] = f2b(v.z);
    Bs[base + 24] = f2b(v.w);
  }
  __syncthreads();

  const int lane = t & 63;
  const int wave = t >> 6;
  const int c16  = lane & 15;
  const int quad = lane >> 4;
  const int rb   = (blk0 * 4 + wave) * 16;

  const int ra = rb + c16;
  const int nodeA = ra / nm;
  const int mA = m0 + (ra - nodeA * nm);
  const size_t abase = ((size_t)nodeA * MTOT + mA) * CH + quad * 8;

  f32x4 acc[8] = {};
  #pragma unroll
  for (int kk = 0; kk < CH; kk += 32) {
    short8 afrag;
    if (XBF) {
      afrag = *(const short8*)((const unsigned short*)Xv + abase + kk);
    } else {
      const float* xp = (const float*)Xv + abase + kk;
      float4 f0 = *(const float4*)xp;
      float4 f1 = *(const float4*)(xp + 4);
      afrag = (short8){(short)f2b(f0.x), (short)f2b(f0.y), (short)f2b(f0.z), (short)f2b(f0.w),
                       (short)f2b(f1.x), (short)f2b(f1.y), (short)f2b(f1.z), (short)f2b(f1.w)};
    }
    const int kq = (kk >> 3) + quad;
    #pragma unroll
    for (int ct = 0; ct < 8; ++ct) {
      short8 bfrag = *(const short8*)&Bs[((ct * 16 + kq) * 16 + c16) * 8];
      acc[ct] = __builtin_amdgcn_mfma_f32_16x16x32_bf16(afrag, bfrag, acc[ct], 0, 0, 0);
    }
  }

  const float scale = NORM ? (l == 0 ? 1.0f : (l == 1 ? S3f : S2f)) : 1.0f;
  #pragma unroll
  for (int i = 0; i < 4; ++i) {
    int r2 = rb + quad * 4 + i;
    int node2 = r2 / nm;
    int m2 = m0 + (r2 - node2 * nm);
    size_t obase = ((size_t)node2 * MTOT + m2) * CH + c16;
    #pragma unroll
    for (int ct = 0; ct < 8; ++ct) {
      float v = acc[ct][i];
      if (l == 0) v += bias[ct * 16 + c16];
      v *= scale;
      if (YBF) ((unsigned short*)Yv)[obase + ct * 16] = f2b(v);
      else     ((float*)Yv)[obase + ct * 16] = v;
    }
  }
}

// ---------------- gather + 4-way aggregate + fused TP, packed-f32 ----------
// block = 256 threads = 4 waves = 4 target nodes; lane handles 2 channels
// packed into f32x2 (targets v_pk_fma_f32); j-loop software-pipelined 2-deep.
__global__ __launch_bounds__(256) void agg_tp_b(
    const unsigned short* __restrict__ X,   // eh1 bf16 [NN,9,128]
    const float* __restrict__ pos,
    const float* __restrict__ exp_pos,
    const float* __restrict__ alpha,
    const int*   __restrict__ idx,
    const float* __restrict__ tpw,
    unsigned short* __restrict__ D)         // diff bf16 [NN,9,128]
{
  __shared__ int   sIdx[4][16];
  __shared__ float sAl[4][128];
  __shared__ float sEy[4][48];
  __shared__ float sY[4][4];
  const int t = threadIdx.x, wave = t >> 6, lane = t & 63;
  const int b = blockIdx.x * 4 + wave;

  if (lane < 16) sIdx[wave][lane] = idx[b * 16 + lane];
  sAl[wave][lane]      = alpha[b * 128 + lane];
  sAl[wave][lane + 64] = alpha[b * 128 + lane + 64];
  if (lane < 3) sY[wave][lane] = YSf * pos[b * 3 + lane];
  __syncthreads();
  if (lane < 48) {
    int j = lane / 3, cmp = lane - 3 * j;
    sEy[wave][lane] = YSf * exp_pos[sIdx[wave][j] * 3 + cmp];
  }
  __syncthreads();

  const int h = lane >> 3;
  const int c0 = lane * 2;
  f32x2 A0[9] = {}, A1[9] = {}, A2[9] = {}, A3[9] = {};
  unsigned va[9], vb[9];

  auto ldrow = [&](unsigned (&v)[9], int j) {
    const unsigned short* xp = X + (size_t)sIdx[wave][j] * (MTOT * CH) + c0;
    #pragma unroll
    for (int m = 0; m < 9; ++m) v[m] = *(const unsigned*)(xp + m * CH);
  };
  auto accum = [&](const unsigned (&v)[9], int j) {
    float al = sAl[wave][j * 8 + h];
    float e0 = al * sEy[wave][j * 3 + 0];
    float e1 = al * sEy[wave][j * 3 + 1];
    float e2 = al * sEy[wave][j * 3 + 2];
    #pragma unroll
    for (int m = 0; m < 9; ++m) {
      f32x2 x;
      x.x = __builtin_bit_cast(float, v[m] << 16);
      x.y = __builtin_bit_cast(float, v[m] & 0xFFFF0000u);
      A0[m] += al * x; A1[m] += e0 * x; A2[m] += e1 * x; A3[m] += e2 * x;
    }
  };

  ldrow(va, 0);
  #pragma unroll
  for (int j = 0; j < 16; j += 2) {
    ldrow(vb, j + 1);
    accum(va, j);
    if (j + 2 < 16) ldrow(va, j + 2);
    accum(vb, j + 1);
  }

  const float y0 = sY[wave][0], yv1 = sY[wave][1], y2 = sY[wave][2];
  const f32x2 w0 = *(const f32x2*)(tpw + 0 * CH + c0);
  const f32x2 w1 = *(const f32x2*)(tpw + 1 * CH + c0);
  const f32x2 w2 = *(const f32x2*)(tpw + 2 * CH + c0);
  const f32x2 w3 = *(const f32x2*)(tpw + 3 * CH + c0);
  const f32x2 w4 = *(const f32x2*)(tpw + 4 * CH + c0);
  const f32x2 w5 = *(const f32x2*)(tpw + 5 * CH + c0);
  const f32x2 x0 = A0[0];
  const f32x2 p0 = A0[1], p1 = A0[2], p2 = A0[3];
  const f32x2 d0 = A0[4], d1 = A0[5], d2 = A0[6], d3 = A0[7], d4 = A0[8];

  unsigned short* dbase = D + (size_t)b * (MTOT * CH) + c0;
  auto st = [&](int m, f32x2 o) {
    unsigned dw = (unsigned)f2b(o.x) | ((unsigned)f2b(o.y) << 16);
    *(unsigned*)(dbase + m * CH) = dw;
  };

  // fused (c1 - c2agg) per output m; q-terms folded into r-terms
  st(0, w1 * (S3f * ((p0 * y0 + p1 * yv1 + p2 * y2) - (A1[1] + A2[2] + A3[3]))));
  st(1, w0 * (x0 * y0 - A1[0])
      + w2 * (S2f * ((p1 * y2 - p2 * yv1) - (A3[2] - A2[3])))
      + w4 * (CUf * ((d0 * y2 + d1 * yv1 - d4 * y0) - (A3[4] + A2[5] - A1[8]))
            - CVf * (d2 * y0 - A1[6])));
  st(2, w0 * (x0 * yv1 - A2[0])
      + w2 * (S2f * ((p2 * y0 - p0 * y2) - (A1[3] - A3[1])))
      + w4 * (CUf * ((d1 * y0 + d3 * y2) - (A1[5] + A3[7]))
            + CWf * (d2 * yv1 - A2[6])));
  st(3, w0 * (x0 * y2 - A3[0])
      + w2 * (S2f * ((p0 * yv1 - p1 * y0) - (A2[1] - A1[2])))
      + w4 * (CUf * ((d0 * y0 + d4 * y2 + d3 * yv1) - (A1[4] + A3[8] + A2[7]))
            - CVf * (d2 * y2 - A3[6])));
  st(4, w3 * (S2f * ((p0 * y2 + p2 * y0) - (A3[1] + A1[3])))
      + w5 * (CAf * ((d3 * y2 - d1 * y0) - (A3[7] - A1[5]))
            - 2.f * CAf * (d4 * yv1 - A2[8])));
  st(5, w3 * (S2f * ((p0 * yv1 + p1 * y0) - (A2[1] + A1[2])))
      + w5 * (CAf * ((d0 * y0 - d3 * yv1 + d4 * y2) - (A1[4] - A2[7] + A3[8]))
            + S2f * (d2 * y2 - A3[6])));
  st(6, w3 * (CA2f * (p1 * yv1 - A2[2]) - CAf * ((p0 * y0 + p2 * y2) - (A1[1] + A3[3])))
      + w5 * (S2f * ((d3 * y0 - d1 * y2) - (A1[7] - A3[5]))));
  st(7, w3 * (S2f * ((p1 * y2 + p2 * yv1) - (A3[2] + A2[3])))
      + w5 * (CAf * ((d1 * yv1 - d0 * y2 + d4 * y0) - (A2[5] - A3[4] + A1[8]))
            - S2f * (d2 * y0 - A1[6])));
  st(8, w3 * (S2f * ((p2 * y2 - p0 * y0) - (A3[3] - A1[1])))
      + w5 * (CAf * (2.f * (d0 * yv1 - A2[4]) - (d1 * y2 - A3[5]) - (d3 * y0 - A1[7]))));
}

extern "C" void kernel_launch(void* const* d_in, const int* in_sizes, int n_in,
                              void* d_out, int out_size, void* d_ws, size_t ws_size,
                              hipStream_t stream) {
  (void)in_sizes; (void)n_in; (void)out_size; (void)ws_size;
  const float* pos     = (const float*)d_in[0];
  const float* exp_pos = (const float*)d_in[1];
  // d_in[2] = h : unused by the reference computation
  const float* exp_h   = (const float*)d_in[3];
  const float* alpha   = (const float*)d_in[4];
  const int*   idx     = (const int*)d_in[5];
  const float* w1w     = (const float*)d_in[6];
  const float* w1b     = (const float*)d_in[7];
  const float* w2w     = (const float*)d_in[8];
  const float* w2b     = (const float*)d_in[9];
  const float* tpw     = (const float*)d_in[10];
  float* out = (float*)d_out;

  unsigned short* eh1 = (unsigned short*)d_ws;                  // bf16 [4096*9*128]
  unsigned short* dif = eh1 + (size_t)NN * MTOT * CH;           // bf16 [4096*9*128]

  so3lin_mfma<0, 1, 0><<<576, 256, 0, stream>>>(exp_h, w1w, w1b, eh1);
  agg_tp_b<<<NN / 4, 256, 0, stream>>>(eh1, pos, exp_pos, alpha, idx, tpw, dif);
  so3lin_mfma<1, 0, 1><<<576, 256, 0, stream>>>(dif, w2w, w2b, out);
}

// Round 4
// 134.444 us; speedup vs baseline: 1.1482x; 1.1482x over previous
//
#include <hip/hip_runtime.h>

#define NN 4096
#define MTOT 9
#define CH 128

// -------- Wigner-3j / TP constants (verified correct in R1/R2 passes) ----
#define S3f 0.57735026918962576f   // 1/sqrt(3)
#define S2f 0.70710678118654752f   // 1/sqrt(2)
#define CUf 0.54772255750516611f   // sqrt(3/10)
#define CVf 0.31622776601683794f   // sqrt(1/10)
#define CWf 0.63245553203367587f   // 2/sqrt(10)
#define CAf 0.40824829046386302f   // 1/sqrt(6)
#define CA2f 0.81649658092772603f  // 2/sqrt(6)
#define YSf ((float)(2.04665350914 * 0.48860251190291992))

typedef __attribute__((ext_vector_type(8))) short short8;
typedef __attribute__((ext_vector_type(4))) float f32x4;

__device__ __forceinline__ unsigned short f2b(float f) {
  unsigned u = __builtin_bit_cast(unsigned, f);
  u += 0x7FFFu + ((u >> 16) & 1u);           // RNE
  return (unsigned short)(u >> 16);
}

// ---------------- W pre-swizzle: fp32 [3,128,128] -> bf16 frag-order -------
// out[l*16384 + (((n>>4)*16 + kq)*16 + (n&15))*8 + j] = W[l][kq*8+j][n]
// One thread per (weight, l, n, kq): 8 strided reads, one 16B store.
__global__ __launch_bounds__(256) void wprep(
    const float* __restrict__ w1, const float* __restrict__ w2,
    unsigned short* __restrict__ o1, unsigned short* __restrict__ o2)
{
  int g = blockIdx.x * 256 + threadIdx.x;    // 12288 total
  const float* W = w1;
  unsigned short* O = o1;
  int r = g;
  if (r >= 6144) { r -= 6144; W = w2; O = o2; }
  int l  = r >> 11;          // 2048 per l
  int r2 = r & 2047;
  int n  = r2 >> 4;
  int kq = r2 & 15;
  const float* src = W + l * 16384 + kq * 8 * CH + n;
  short8 v;
  #pragma unroll
  for (int j = 0; j < 8; ++j) v[j] = (short)f2b(src[j * CH]);
  *(short8*)(O + (size_t)l * 16384 + (((n >> 4) * 16 + kq) * 16 + (n & 15)) * 8) = v;
}

// ---------------- so3_linear via MFMA 16x16x32 bf16 ----------------
// W arrives pre-swizzled bf16; staging is 8 contiguous dwordx4 + b128 writes.
template <int XBF, int YBF, int NORM>
__global__ __launch_bounds__(256) void so3lin_mfma(
    const void* __restrict__ Xv, const unsigned short* __restrict__ Wsw,
    const float* __restrict__ bias, void* __restrict__ Yv)
{
  __shared__ unsigned short Bs[16384];   // 32 KB frag-order bf16 W_l
  const int bid = blockIdx.x;
  int l, blk0, m0, nm;
  if (bid < 64)       { l = 0; blk0 = bid;       m0 = 0; nm = 1; }
  else if (bid < 256) { l = 1; blk0 = bid - 64;  m0 = 1; nm = 3; }
  else                { l = 2; blk0 = bid - 256; m0 = 4; nm = 5; }
  const int t = threadIdx.x;

  {
    const float4* src = (const float4*)(Wsw + (size_t)l * 16384);
    float4* dst = (float4*)Bs;
    #pragma unroll
    for (int i = 0; i < 8; ++i) dst[t + i * 256] = src[t + i * 256];
  }
  __syncthreads();

  const int lane = t & 63;
  const int wave = t >> 6;
  const int c16  = lane & 15;
  const int quad = lane >> 4;
  const int rb   = (blk0 * 4 + wave) * 16;

  const int ra = rb + c16;
  const int nodeA = ra / nm;
  const int mA = m0 + (ra - nodeA * nm);
  const size_t abase = ((size_t)nodeA * MTOT + mA) * CH + quad * 8;

  f32x4 acc[8] = {};
  #pragma unroll
  for (int kk = 0; kk < CH; kk += 32) {
    short8 afrag;
    if (XBF) {
      afrag = *(const short8*)((const unsigned short*)Xv + abase + kk);
    } else {
      const float* xp = (const float*)Xv + abase + kk;
      float4 f0 = *(const float4*)xp;
      float4 f1 = *(const float4*)(xp + 4);
      afrag = (short8){(short)f2b(f0.x), (short)f2b(f0.y), (short)f2b(f0.z), (short)f2b(f0.w),
                       (short)f2b(f1.x), (short)f2b(f1.y), (short)f2b(f1.z), (short)f2b(f1.w)};
    }
    const int kq = (kk >> 3) + quad;
    #pragma unroll
    for (int ct = 0; ct < 8; ++ct) {
      short8 bfrag = *(const short8*)&Bs[((ct * 16 + kq) * 16 + c16) * 8];
      acc[ct] = __builtin_amdgcn_mfma_f32_16x16x32_bf16(afrag, bfrag, acc[ct], 0, 0, 0);
    }
  }

  const float scale = NORM ? (l == 0 ? 1.0f : (l == 1 ? S3f : S2f)) : 1.0f;
  #pragma unroll
  for (int i = 0; i < 4; ++i) {
    int r2 = rb + quad * 4 + i;
    int node2 = r2 / nm;
    int m2 = m0 + (r2 - node2 * nm);
    size_t obase = ((size_t)node2 * MTOT + m2) * CH + c16;
    #pragma unroll
    for (int ct = 0; ct < 8; ++ct) {
      float v = acc[ct][i];
      if (l == 0) v += bias[ct * 16 + c16];
      v *= scale;
      if (YBF) ((unsigned short*)Yv)[obase + ct * 16] = f2b(v);
      else     ((float*)Yv)[obase + ct * 16] = v;
    }
  }
}

// ---------------- gather + 4-way aggregate + fused TP (R2-proven version) --
__global__ __launch_bounds__(256) void agg_tp_b(
    const unsigned short* __restrict__ X,   // eh1 bf16 [NN,9,128]
    const float* __restrict__ pos,
    const float* __restrict__ exp_pos,
    const float* __restrict__ alpha,
    const int*   __restrict__ idx,
    const float* __restrict__ tpw,
    unsigned short* __restrict__ D)         // diff bf16 [NN,9,128]
{
  __shared__ int   sIdx[4][16];
  __shared__ float sAl[4][128];
  __shared__ float sEy[4][48];
  __shared__ float sY[4][4];
  const int t = threadIdx.x, wave = t >> 6, lane = t & 63;
  const int b = blockIdx.x * 4 + wave;

  if (lane < 16) sIdx[wave][lane] = idx[b * 16 + lane];
  sAl[wave][lane]      = alpha[b * 128 + lane];
  sAl[wave][lane + 64] = alpha[b * 128 + lane + 64];
  if (lane < 3) sY[wave][lane] = YSf * pos[b * 3 + lane];
  __syncthreads();
  if (lane < 48) {
    int j = lane / 3, cmp = lane - 3 * j;
    sEy[wave][lane] = YSf * exp_pos[sIdx[wave][j] * 3 + cmp];
  }
  __syncthreads();

  const int h = lane >> 3;
  const int c0 = lane * 2;
  float A0[9][2] = {}, A1[9][2] = {}, A2[9][2] = {}, A3[9][2] = {};
  for (int j = 0; j < 16; ++j) {
    float al = sAl[wave][j * 8 + h];
    float e0 = al * sEy[wave][j * 3 + 0];
    float e1 = al * sEy[wave][j * 3 + 1];
    float e2 = al * sEy[wave][j * 3 + 2];
    const unsigned short* xp = X + (size_t)sIdx[wave][j] * (MTOT * CH) + c0;
    #pragma unroll
    for (int m = 0; m < 9; ++m) {
      unsigned v = *(const unsigned*)(xp + m * CH);
      float x0 = __builtin_bit_cast(float, v << 16);
      float x1 = __builtin_bit_cast(float, v & 0xFFFF0000u);
      A0[m][0] += al * x0; A1[m][0] += e0 * x0; A2[m][0] += e1 * x0; A3[m][0] += e2 * x0;
      A0[m][1] += al * x1; A1[m][1] += e0 * x1; A2[m][1] += e1 * x1; A3[m][1] += e2 * x1;
    }
  }

  const float y0 = sY[wave][0], yv1 = sY[wave][1], y2 = sY[wave][2];
  float OUT[9][2];
  #pragma unroll
  for (int ch = 0; ch < 2; ++ch) {
    const int c = c0 + ch;
    const float w0 = tpw[c], w1 = tpw[CH + c], w2 = tpw[2 * CH + c];
    const float w3 = tpw[3 * CH + c], w4 = tpw[4 * CH + c], w5 = tpw[5 * CH + c];
    const float x0 = A0[0][ch];
    const float p0 = A0[1][ch], p1 = A0[2][ch], p2 = A0[3][ch];
    const float d0 = A0[4][ch], d1 = A0[5][ch], d2 = A0[6][ch], d3 = A0[7][ch], d4 = A0[8][ch];

    float r0 = w1 * S3f * (p0 * y0 + p1 * yv1 + p2 * y2);
    float r1 = w0 * x0 * y0 + w2 * S2f * (p1 * y2 - p2 * yv1)
             + w4 * (CUf * (d0 * y2 + d1 * yv1 - d4 * y0) - CVf * d2 * y0);
    float r2 = w0 * x0 * yv1 + w2 * S2f * (p2 * y0 - p0 * y2)
             + w4 * (CUf * (d1 * y0 + d3 * y2) + CWf * d2 * yv1);
    float r3 = w0 * x0 * y2 + w2 * S2f * (p0 * yv1 - p1 * y0)
             + w4 * (CUf * (d0 * y0 + d4 * y2 + d3 * yv1) - CVf * d2 * y2);
    float r4 = w3 * S2f * (p0 * y2 + p2 * y0)
             + w5 * (CAf * (d3 * y2 - d1 * y0) - 2.f * CAf * d4 * yv1);
    float r5 = w3 * S2f * (p0 * yv1 + p1 * y0)
             + w5 * (CAf * (d0 * y0 - d3 * yv1 + d4 * y2) + S2f * d2 * y2);
    float r6 = w3 * (CA2f * p1 * yv1 - CAf * (p0 * y0 + p2 * y2))
             + w5 * S2f * (d3 * y0 - d1 * y2);
    float r7 = w3 * S2f * (p1 * y2 + p2 * yv1)
             + w5 * (CAf * (d1 * yv1 - d0 * y2 + d4 * y0) - S2f * d2 * y0);
    float r8 = w3 * S2f * (p2 * y2 - p0 * y0)
             + w5 * CAf * (2.f * d0 * yv1 - d1 * y2 - d3 * y0);

    float q0 = w1 * S3f * (A1[1][ch] + A2[2][ch] + A3[3][ch]);
    float q1 = w0 * A1[0][ch] + w2 * S2f * (A3[2][ch] - A2[3][ch])
             + w4 * (CUf * (A3[4][ch] + A2[5][ch] - A1[8][ch]) - CVf * A1[6][ch]);
    float q2 = w0 * A2[0][ch] + w2 * S2f * (A1[3][ch] - A3[1][ch])
             + w4 * (CUf * (A1[5][ch] + A3[7][ch]) + CWf * A2[6][ch]);
    float q3 = w0 * A3[0][ch] + w2 * S2f * (A2[1][ch] - A1[2][ch])
             + w4 * (CUf * (A1[4][ch] + A3[8][ch] + A2[7][ch]) - CVf * A3[6][ch]);
    float q4 = w3 * S2f * (A3[1][ch] + A1[3][ch])
             + w5 * (CAf * (A3[7][ch] - A1[5][ch]) - 2.f * CAf * A2[8][ch]);
    float q5 = w3 * S2f * (A2[1][ch] + A1[2][ch])
             + w5 * (CAf * (A1[4][ch] - A2[7][ch] + A3[8][ch]) + S2f * A3[6][ch]);
    float q6 = w3 * (CA2f * A2[2][ch] - CAf * (A1[1][ch] + A3[3][ch]))
             + w5 * S2f * (A1[7][ch] - A3[5][ch]);
    float q7 = w3 * S2f * (A3[2][ch] + A2[3][ch])
             + w5 * (CAf * (A2[5][ch] - A3[4][ch] + A1[8][ch]) - S2f * A1[6][ch]);
    float q8 = w3 * S2f * (A3[3][ch] - A1[1][ch])
             + w5 * CAf * (2.f * A2[4][ch] - A3[5][ch] - A1[7][ch]);

    OUT[0][ch] = r0 - q0; OUT[1][ch] = r1 - q1; OUT[2][ch] = r2 - q2;
    OUT[3][ch] = r3 - q3; OUT[4][ch] = r4 - q4; OUT[5][ch] = r5 - q5;
    OUT[6][ch] = r6 - q6; OUT[7][ch] = r7 - q7; OUT[8][ch] = r8 - q8;
  }

  #pragma unroll
  for (int m = 0; m < 9; ++m) {
    unsigned dw = (unsigned)f2b(OUT[m][0]) | ((unsigned)f2b(OUT[m][1]) << 16);
    *(unsigned*)(D + ((size_t)b * MTOT + m) * CH + c0) = dw;
  }
}

extern "C" void kernel_launch(void* const* d_in, const int* in_sizes, int n_in,
                              void* d_out, int out_size, void* d_ws, size_t ws_size,
                              hipStream_t stream) {
  (void)in_sizes; (void)n_in; (void)out_size; (void)ws_size;
  const float* pos     = (const float*)d_in[0];
  const float* exp_pos = (const float*)d_in[1];
  // d_in[2] = h : unused by the reference computation
  const float* exp_h   = (const float*)d_in[3];
  const float* alpha   = (const float*)d_in[4];
  const int*   idx     = (const int*)d_in[5];
  const float* w1w     = (const float*)d_in[6];
  const float* w1b     = (const float*)d_in[7];
  const float* w2w     = (const float*)d_in[8];
  const float* w2b     = (const float*)d_in[9];
  const float* tpw     = (const float*)d_in[10];
  float* out = (float*)d_out;

  unsigned short* eh1 = (unsigned short*)d_ws;                  // bf16 [4096*9*128]
  unsigned short* dif = eh1 + (size_t)NN * MTOT * CH;           // bf16 [4096*9*128]
  unsigned short* w1s = dif + (size_t)NN * MTOT * CH;           // bf16 swizzled [3*16384]
  unsigned short* w2s = w1s + 3 * 16384;                        // bf16 swizzled [3*16384]

  wprep<<<48, 256, 0, stream>>>(w1w, w2w, w1s, w2s);
  so3lin_mfma<0, 1, 0><<<576, 256, 0, stream>>>(exp_h, w1s, w1b, eh1);
  agg_tp_b<<<NN / 4, 256, 0, stream>>>(eh1, pos, exp_pos, alpha, idx, tpw, dif);
  so3lin_mfma<1, 0, 1><<<576, 256, 0, stream>>>(dif, w2s, w2b, out);
}

// Round 5
// 133.626 us; speedup vs baseline: 1.1552x; 1.0061x over previous
//
#include <hip/hip_runtime.h>

#define NN 4096
#define MTOT 9
#define CH 128

// -------- Wigner-3j / TP constants (verified correct in R1/R2 passes) ----
#define S3f 0.57735026918962576f   // 1/sqrt(3)
#define S2f 0.70710678118654752f   // 1/sqrt(2)
#define CUf 0.54772255750516611f   // sqrt(3/10)
#define CVf 0.31622776601683794f   // sqrt(1/10)
#define CWf 0.63245553203367587f   // 2/sqrt(10)
#define CAf 0.40824829046386302f   // 1/sqrt(6)
#define CA2f 0.81649658092772603f  // 2/sqrt(6)
#define YSf ((float)(2.04665350914 * 0.48860251190291992))

typedef __attribute__((ext_vector_type(8))) short short8;
typedef __attribute__((ext_vector_type(4))) float f32x4;

__device__ __forceinline__ unsigned short f2b(float f) {
  unsigned u = __builtin_bit_cast(unsigned, f);
  u += 0x7FFFu + ((u >> 16) & 1u);           // RNE
  return (unsigned short)(u >> 16);
}

// ---------------- W pre-swizzle: fp32 [3,128,128] -> bf16 frag-order -------
// out[l*16384 + (((n>>4)*16 + kq)*16 + (n&15))*8 + j] = W[l][kq*8+j][n]
__global__ __launch_bounds__(256) void wprep(
    const float* __restrict__ w1, const float* __restrict__ w2,
    unsigned short* __restrict__ o1, unsigned short* __restrict__ o2)
{
  int g = blockIdx.x * 256 + threadIdx.x;    // 12288 total
  const float* W = w1;
  unsigned short* O = o1;
  int r = g;
  if (r >= 6144) { r -= 6144; W = w2; O = o2; }
  int l  = r >> 11;          // 2048 per l
  int r2 = r & 2047;
  int n  = r2 >> 4;
  int kq = r2 & 15;
  const float* src = W + l * 16384 + kq * 8 * CH + n;
  short8 v;
  #pragma unroll
  for (int j = 0; j < 8; ++j) v[j] = (short)f2b(src[j * CH]);
  *(short8*)(O + (size_t)l * 16384 + (((n >> 4) * 16 + kq) * 16 + (n & 15)) * 8) = v;
}

// ---------------- so3_linear via MFMA 16x16x32 bf16 ----------------
// W arrives pre-swizzled bf16; staging is 8 contiguous dwordx4 + b128 writes.
template <int XBF, int YBF, int NORM>
__global__ __launch_bounds__(256) void so3lin_mfma(
    const void* __restrict__ Xv, const unsigned short* __restrict__ Wsw,
    const float* __restrict__ bias, void* __restrict__ Yv)
{
  __shared__ unsigned short Bs[16384];   // 32 KB frag-order bf16 W_l
  const int bid = blockIdx.x;
  int l, blk0, m0, nm;
  if (bid < 64)       { l = 0; blk0 = bid;       m0 = 0; nm = 1; }
  else if (bid < 256) { l = 1; blk0 = bid - 64;  m0 = 1; nm = 3; }
  else                { l = 2; blk0 = bid - 256; m0 = 4; nm = 5; }
  const int t = threadIdx.x;

  {
    const float4* src = (const float4*)(Wsw + (size_t)l * 16384);
    float4* dst = (float4*)Bs;
    #pragma unroll
    for (int i = 0; i < 8; ++i) dst[t + i * 256] = src[t + i * 256];
  }
  __syncthreads();

  const int lane = t & 63;
  const int wave = t >> 6;
  const int c16  = lane & 15;
  const int quad = lane >> 4;
  const int rb   = (blk0 * 4 + wave) * 16;

  const int ra = rb + c16;
  const int nodeA = ra / nm;
  const int mA = m0 + (ra - nodeA * nm);
  const size_t abase = ((size_t)nodeA * MTOT + mA) * CH + quad * 8;

  f32x4 acc[8] = {};
  #pragma unroll
  for (int kk = 0; kk < CH; kk += 32) {
    short8 afrag;
    if (XBF) {
      afrag = *(const short8*)((const unsigned short*)Xv + abase + kk);
    } else {
      const float* xp = (const float*)Xv + abase + kk;
      float4 f0 = *(const float4*)xp;
      float4 f1 = *(const float4*)(xp + 4);
      afrag = (short8){(short)f2b(f0.x), (short)f2b(f0.y), (short)f2b(f0.z), (short)f2b(f0.w),
                       (short)f2b(f1.x), (short)f2b(f1.y), (short)f2b(f1.z), (short)f2b(f1.w)};
    }
    const int kq = (kk >> 3) + quad;
    #pragma unroll
    for (int ct = 0; ct < 8; ++ct) {
      short8 bfrag = *(const short8*)&Bs[((ct * 16 + kq) * 16 + c16) * 8];
      acc[ct] = __builtin_amdgcn_mfma_f32_16x16x32_bf16(afrag, bfrag, acc[ct], 0, 0, 0);
    }
  }

  const float scale = NORM ? (l == 0 ? 1.0f : (l == 1 ? S3f : S2f)) : 1.0f;
  #pragma unroll
  for (int i = 0; i < 4; ++i) {
    int r2 = rb + quad * 4 + i;
    int node2 = r2 / nm;
    int m2 = m0 + (r2 - node2 * nm);
    size_t obase = ((size_t)node2 * MTOT + m2) * CH + c16;
    #pragma unroll
    for (int ct = 0; ct < 8; ++ct) {
      float v = acc[ct][i];
      if (l == 0) v += bias[ct * 16 + c16];
      v *= scale;
      if (YBF) ((unsigned short*)Yv)[obase + ct * 16] = f2b(v);
      else     ((float*)Yv)[obase + ct * 16] = v;
    }
  }
}

// ---------------- gather + 4-way aggregate + fused TP (R2 core + unroll 2) -
__global__ __launch_bounds__(256) void agg_tp_b(
    const unsigned short* __restrict__ X,   // eh1 bf16 [NN,9,128]
    const float* __restrict__ pos,
    const float* __restrict__ exp_pos,
    const float* __restrict__ alpha,
    const int*   __restrict__ idx,
    const float* __restrict__ tpw,
    unsigned short* __restrict__ D)         // diff bf16 [NN,9,128]
{
  __shared__ int   sIdx[4][16];
  __shared__ float sAl[4][128];
  __shared__ float sEy[4][48];
  __shared__ float sY[4][4];
  const int t = threadIdx.x, wave = t >> 6, lane = t & 63;
  const int b = blockIdx.x * 4 + wave;

  if (lane < 16) sIdx[wave][lane] = idx[b * 16 + lane];
  sAl[wave][lane]      = alpha[b * 128 + lane];
  sAl[wave][lane + 64] = alpha[b * 128 + lane + 64];
  if (lane < 3) sY[wave][lane] = YSf * pos[b * 3 + lane];
  __syncthreads();
  if (lane < 48) {
    int j = lane / 3, cmp = lane - 3 * j;
    sEy[wave][lane] = YSf * exp_pos[sIdx[wave][j] * 3 + cmp];
  }
  __syncthreads();

  const int h = lane >> 3;
  const int c0 = lane * 2;
  float A0[9][2] = {}, A1[9][2] = {}, A2[9][2] = {}, A3[9][2] = {};
  // unroll 2: compiler batches two rows' loads -> group latency ~= group VALU
  #pragma unroll 2
  for (int j = 0; j < 16; ++j) {
    float al = sAl[wave][j * 8 + h];
    float e0 = al * sEy[wave][j * 3 + 0];
    float e1 = al * sEy[wave][j * 3 + 1];
    float e2 = al * sEy[wave][j * 3 + 2];
    const unsigned short* xp = X + (size_t)sIdx[wave][j] * (MTOT * CH) + c0;
    #pragma unroll
    for (int m = 0; m < 9; ++m) {
      unsigned v = *(const unsigned*)(xp + m * CH);
      float x0 = __builtin_bit_cast(float, v << 16);
      float x1 = __builtin_bit_cast(float, v & 0xFFFF0000u);
      A0[m][0] += al * x0; A1[m][0] += e0 * x0; A2[m][0] += e1 * x0; A3[m][0] += e2 * x0;
      A0[m][1] += al * x1; A1[m][1] += e0 * x1; A2[m][1] += e1 * x1; A3[m][1] += e2 * x1;
    }
  }

  const float y0 = sY[wave][0], yv1 = sY[wave][1], y2 = sY[wave][2];
  float OUT[9][2];
  #pragma unroll
  for (int ch = 0; ch < 2; ++ch) {
    const int c = c0 + ch;
    const float w0 = tpw[c], w1 = tpw[CH + c], w2 = tpw[2 * CH + c];
    const float w3 = tpw[3 * CH + c], w4 = tpw[4 * CH + c], w5 = tpw[5 * CH + c];
    const float x0 = A0[0][ch];
    const float p0 = A0[1][ch], p1 = A0[2][ch], p2 = A0[3][ch];
    const float d0 = A0[4][ch], d1 = A0[5][ch], d2 = A0[6][ch], d3 = A0[7][ch], d4 = A0[8][ch];

    float r0 = w1 * S3f * (p0 * y0 + p1 * yv1 + p2 * y2);
    float r1 = w0 * x0 * y0 + w2 * S2f * (p1 * y2 - p2 * yv1)
             + w4 * (CUf * (d0 * y2 + d1 * yv1 - d4 * y0) - CVf * d2 * y0);
    float r2 = w0 * x0 * yv1 + w2 * S2f * (p2 * y0 - p0 * y2)
             + w4 * (CUf * (d1 * y0 + d3 * y2) + CWf * d2 * yv1);
    float r3 = w0 * x0 * y2 + w2 * S2f * (p0 * yv1 - p1 * y0)
             + w4 * (CUf * (d0 * y0 + d4 * y2 + d3 * yv1) - CVf * d2 * y2);
    float r4 = w3 * S2f * (p0 * y2 + p2 * y0)
             + w5 * (CAf * (d3 * y2 - d1 * y0) - 2.f * CAf * d4 * yv1);
    float r5 = w3 * S2f * (p0 * yv1 + p1 * y0)
             + w5 * (CAf * (d0 * y0 - d3 * yv1 + d4 * y2) + S2f * d2 * y2);
    float r6 = w3 * (CA2f * p1 * yv1 - CAf * (p0 * y0 + p2 * y2))
             + w5 * S2f * (d3 * y0 - d1 * y2);
    float r7 = w3 * S2f * (p1 * y2 + p2 * yv1)
             + w5 * (CAf * (d1 * yv1 - d0 * y2 + d4 * y0) - S2f * d2 * y0);
    float r8 = w3 * S2f * (p2 * y2 - p0 * y0)
             + w5 * CAf * (2.f * d0 * yv1 - d1 * y2 - d3 * y0);

    float q0 = w1 * S3f * (A1[1][ch] + A2[2][ch] + A3[3][ch]);
    float q1 = w0 * A1[0][ch] + w2 * S2f * (A3[2][ch] - A2[3][ch])
             + w4 * (CUf * (A3[4][ch] + A2[5][ch] - A1[8][ch]) - CVf * A1[6][ch]);
    float q2 = w0 * A2[0][ch] + w2 * S2f * (A1[3][ch] - A3[1][ch])
             + w4 * (CUf * (A1[5][ch] + A3[7][ch]) + CWf * A2[6][ch]);
    float q3 = w0 * A3[0][ch] + w2 * S2f * (A2[1][ch] - A1[2][ch])
             + w4 * (CUf * (A1[4][ch] + A3[8][ch] + A2[7][ch]) - CVf * A3[6][ch]);
    float q4 = w3 * S2f * (A3[1][ch] + A1[3][ch])
             + w5 * (CAf * (A3[7][ch] - A1[5][ch]) - 2.f * CAf * A2[8][ch]);
    float q5 = w3 * S2f * (A2[1][ch] + A1[2][ch])
             + w5 * (CAf * (A1[4][ch] - A2[7][ch] + A3[8][ch]) + S2f * A3[6][ch]);
    float q6 = w3 * (CA2f * A2[2][ch] - CAf * (A1[1][ch] + A3[3][ch]))
             + w5 * S2f * (A1[7][ch] - A3[5][ch]);
    float q7 = w3 * S2f * (A3[2][ch] + A2[3][ch])
             + w5 * (CAf * (A2[5][ch] - A3[4][ch] + A1[8][ch]) - S2f * A1[6][ch]);
    float q8 = w3 * S2f * (A3[3][ch] - A1[1][ch])
             + w5 * CAf * (2.f * A2[4][ch] - A3[5][ch] - A1[7][ch]);

    OUT[0][ch] = r0 - q0; OUT[1][ch] = r1 - q1; OUT[2][ch] = r2 - q2;
    OUT[3][ch] = r3 - q3; OUT[4][ch] = r4 - q4; OUT[5][ch] = r5 - q5;
    OUT[6][ch] = r6 - q6; OUT[7][ch] = r7 - q7; OUT[8][ch] = r8 - q8;
  }

  #pragma unroll
  for (int m = 0; m < 9; ++m) {
    unsigned dw = (unsigned)f2b(OUT[m][0]) | ((unsigned)f2b(OUT[m][1]) << 16);
    *(unsigned*)(D + ((size_t)b * MTOT + m) * CH + c0) = dw;
  }
}

extern "C" void kernel_launch(void* const* d_in, const int* in_sizes, int n_in,
                              void* d_out, int out_size, void* d_ws, size_t ws_size,
                              hipStream_t stream) {
  (void)in_sizes; (void)n_in; (void)out_size; (void)ws_size;
  const float* pos     = (const float*)d_in[0];
  const float* exp_pos = (const float*)d_in[1];
  // d_in[2] = h : unused by the reference computation
  const float* exp_h   = (const float*)d_in[3];
  const float* alpha   = (const float*)d_in[4];
  const int*   idx     = (const int*)d_in[5];
  const float* w1w     = (const float*)d_in[6];
  const float* w1b     = (const float*)d_in[7];
  const float* w2w     = (const float*)d_in[8];
  const float* w2b     = (const float*)d_in[9];
  const float* tpw     = (const float*)d_in[10];
  float* out = (float*)d_out;

  unsigned short* eh1 = (unsigned short*)d_ws;                  // bf16 [4096*9*128]
  unsigned short* dif = eh1 + (size_t)NN * MTOT * CH;           // bf16 [4096*9*128]
  unsigned short* w1s = dif + (size_t)NN * MTOT * CH;           // bf16 swizzled [3*16384]
  unsigned short* w2s = w1s + 3 * 16384;                        // bf16 swizzled [3*16384]

  wprep<<<48, 256, 0, stream>>>(w1w, w2w, w1s, w2s);
  so3lin_mfma<0, 1, 0><<<576, 256, 0, stream>>>(exp_h, w1s, w1b, eh1);
  agg_tp_b<<<NN / 4, 256, 0, stream>>>(eh1, pos, exp_pos, alpha, idx, tpw, dif);
  so3lin_mfma<1, 0, 1><<<576, 256, 0, stream>>>(dif, w2s, w2b, out);
}

// Round 6
// 133.430 us; speedup vs baseline: 1.1569x; 1.0015x over previous
//
#include <hip/hip_runtime.h>

#define NN 4096
#define MTOT 9
#define CH 128

// -------- Wigner-3j / TP constants (verified correct in R1/R2 passes) ----
#define S3f 0.57735026918962576f   // 1/sqrt(3)
#define S2f 0.70710678118654752f   // 1/sqrt(2)
#define CUf 0.54772255750516611f   // sqrt(3/10)
#define CVf 0.31622776601683794f   // sqrt(1/10)
#define CWf 0.63245553203367587f   // 2/sqrt(10)
#define CAf 0.40824829046386302f   // 1/sqrt(6)
#define CA2f 0.81649658092772603f  // 2/sqrt(6)
#define YSf ((float)(2.04665350914 * 0.48860251190291992))

typedef __attribute__((ext_vector_type(8))) short short8;
typedef __attribute__((ext_vector_type(4))) float f32x4;
typedef __attribute__((ext_vector_type(2))) float f32x2;

__device__ __forceinline__ unsigned short f2b(float f) {
  unsigned u = __builtin_bit_cast(unsigned, f);
  u += 0x7FFFu + ((u >> 16) & 1u);           // RNE
  return (unsigned short)(u >> 16);
}

// ---------------- W pre-swizzle: fp32 [3,128,128] -> bf16 frag-order -------
// out[l*16384 + (((n>>4)*16 + kq)*16 + (n&15))*8 + j] = W[l][kq*8+j][n]
__global__ __launch_bounds__(256) void wprep(
    const float* __restrict__ w1, const float* __restrict__ w2,
    unsigned short* __restrict__ o1, unsigned short* __restrict__ o2)
{
  int g = blockIdx.x * 256 + threadIdx.x;    // 12288 total
  const float* W = w1;
  unsigned short* O = o1;
  int r = g;
  if (r >= 6144) { r -= 6144; W = w2; O = o2; }
  int l  = r >> 11;          // 2048 per l
  int r2 = r & 2047;
  int n  = r2 >> 4;
  int kq = r2 & 15;
  const float* src = W + l * 16384 + kq * 8 * CH + n;
  short8 v;
  #pragma unroll
  for (int j = 0; j < 8; ++j) v[j] = (short)f2b(src[j * CH]);
  *(short8*)(O + (size_t)l * 16384 + (((n >> 4) * 16 + kq) * 16 + (n & 15)) * 8) = v;
}

// ---------------- so3_linear via MFMA 16x16x32 bf16 ----------------
// W arrives pre-swizzled bf16; staging is 8 contiguous dwordx4 + b128 writes.
template <int XBF, int YBF, int NORM>
__global__ __launch_bounds__(256) void so3lin_mfma(
    const void* __restrict__ Xv, const unsigned short* __restrict__ Wsw,
    const float* __restrict__ bias, void* __restrict__ Yv)
{
  __shared__ unsigned short Bs[16384];   // 32 KB frag-order bf16 W_l
  const int bid = blockIdx.x;
  int l, blk0, m0, nm;
  if (bid < 64)       { l = 0; blk0 = bid;       m0 = 0; nm = 1; }
  else if (bid < 256) { l = 1; blk0 = bid - 64;  m0 = 1; nm = 3; }
  else                { l = 2; blk0 = bid - 256; m0 = 4; nm = 5; }
  const int t = threadIdx.x;

  {
    const float4* src = (const float4*)(Wsw + (size_t)l * 16384);
    float4* dst = (float4*)Bs;
    #pragma unroll
    for (int i = 0; i < 8; ++i) dst[t + i * 256] = src[t + i * 256];
  }
  __syncthreads();

  const int lane = t & 63;
  const int wave = t >> 6;
  const int c16  = lane & 15;
  const int quad = lane >> 4;
  const int rb   = (blk0 * 4 + wave) * 16;

  const int ra = rb + c16;
  const int nodeA = ra / nm;
  const int mA = m0 + (ra - nodeA * nm);
  const size_t abase = ((size_t)nodeA * MTOT + mA) * CH + quad * 8;

  f32x4 acc[8] = {};
  #pragma unroll
  for (int kk = 0; kk < CH; kk += 32) {
    short8 afrag;
    if (XBF) {
      afrag = *(const short8*)((const unsigned short*)Xv + abase + kk);
    } else {
      const float* xp = (const float*)Xv + abase + kk;
      float4 f0 = *(const float4*)xp;
      float4 f1 = *(const float4*)(xp + 4);
      afrag = (short8){(short)f2b(f0.x), (short)f2b(f0.y), (short)f2b(f0.z), (short)f2b(f0.w),
                       (short)f2b(f1.x), (short)f2b(f1.y), (short)f2b(f1.z), (short)f2b(f1.w)};
    }
    const int kq = (kk >> 3) + quad;
    #pragma unroll
    for (int ct = 0; ct < 8; ++ct) {
      short8 bfrag = *(const short8*)&Bs[((ct * 16 + kq) * 16 + c16) * 8];
      acc[ct] = __builtin_amdgcn_mfma_f32_16x16x32_bf16(afrag, bfrag, acc[ct], 0, 0, 0);
    }
  }

  const float scale = NORM ? (l == 0 ? 1.0f : (l == 1 ? S3f : S2f)) : 1.0f;
  #pragma unroll
  for (int i = 0; i < 4; ++i) {
    int r2 = rb + quad * 4 + i;
    int node2 = r2 / nm;
    int m2 = m0 + (r2 - node2 * nm);
    size_t obase = ((size_t)node2 * MTOT + m2) * CH + c16;
    #pragma unroll
    for (int ct = 0; ct < 8; ++ct) {
      float v = acc[ct][i];
      if (l == 0) v += bias[ct * 16 + c16];
      v *= scale;
      if (YBF) ((unsigned short*)Yv)[obase + ct * 16] = f2b(v);
      else     ((float*)Yv)[obase + ct * 16] = v;
    }
  }
}

// ---------------- gather + 4-way aggregate + fused TP ----------------------
// R4 structure; accumulators packed f32x2 -> v_pk_fma_f32 (halves FMA count)
__global__ __launch_bounds__(256) void agg_tp_b(
    const unsigned short* __restrict__ X,   // eh1 bf16 [NN,9,128]
    const float* __restrict__ pos,
    const float* __restrict__ exp_pos,
    const float* __restrict__ alpha,
    const int*   __restrict__ idx,
    const float* __restrict__ tpw,
    unsigned short* __restrict__ D)         // diff bf16 [NN,9,128]
{
  __shared__ int   sIdx[4][16];
  __shared__ float sAl[4][128];
  __shared__ float sEy[4][48];
  __shared__ float sY[4][4];
  const int t = threadIdx.x, wave = t >> 6, lane = t & 63;
  const int b = blockIdx.x * 4 + wave;

  if (lane < 16) sIdx[wave][lane] = idx[b * 16 + lane];
  sAl[wave][lane]      = alpha[b * 128 + lane];
  sAl[wave][lane + 64] = alpha[b * 128 + lane + 64];
  if (lane < 3) sY[wave][lane] = YSf * pos[b * 3 + lane];
  __syncthreads();
  if (lane < 48) {
    int j = lane / 3, cmp = lane - 3 * j;
    sEy[wave][lane] = YSf * exp_pos[sIdx[wave][j] * 3 + cmp];
  }
  __syncthreads();

  const int h = lane >> 3;
  const int c0 = lane * 2;
  f32x2 A0[9] = {}, A1[9] = {}, A2[9] = {}, A3[9] = {};
  #pragma unroll 2
  for (int j = 0; j < 16; ++j) {
    float al = sAl[wave][j * 8 + h];
    float e0 = al * sEy[wave][j * 3 + 0];
    float e1 = al * sEy[wave][j * 3 + 1];
    float e2 = al * sEy[wave][j * 3 + 2];
    f32x2 alv = {al, al};
    f32x2 e0v = {e0, e0};
    f32x2 e1v = {e1, e1};
    f32x2 e2v = {e2, e2};
    const unsigned short* xp = X + (size_t)sIdx[wave][j] * (MTOT * CH) + c0;
    #pragma unroll
    for (int m = 0; m < 9; ++m) {
      unsigned v = *(const unsigned*)(xp + m * CH);
      f32x2 x;
      x.x = __builtin_bit_cast(float, v << 16);
      x.y = __builtin_bit_cast(float, v & 0xFFFF0000u);
      A0[m] += alv * x; A1[m] += e0v * x; A2[m] += e1v * x; A3[m] += e2v * x;
    }
  }

  const float y0 = sY[wave][0], yv1 = sY[wave][1], y2 = sY[wave][2];
  float OUT[9][2];
  #pragma unroll
  for (int ch = 0; ch < 2; ++ch) {
    const int c = c0 + ch;
    const float w0 = tpw[c], w1 = tpw[CH + c], w2 = tpw[2 * CH + c];
    const float w3 = tpw[3 * CH + c], w4 = tpw[4 * CH + c], w5 = tpw[5 * CH + c];
    const float x0 = A0[0][ch];
    const float p0 = A0[1][ch], p1 = A0[2][ch], p2 = A0[3][ch];
    const float d0 = A0[4][ch], d1 = A0[5][ch], d2 = A0[6][ch], d3 = A0[7][ch], d4 = A0[8][ch];

    float r0 = w1 * S3f * (p0 * y0 + p1 * yv1 + p2 * y2);
    float r1 = w0 * x0 * y0 + w2 * S2f * (p1 * y2 - p2 * yv1)
             + w4 * (CUf * (d0 * y2 + d1 * yv1 - d4 * y0) - CVf * d2 * y0);
    float r2 = w0 * x0 * yv1 + w2 * S2f * (p2 * y0 - p0 * y2)
             + w4 * (CUf * (d1 * y0 + d3 * y2) + CWf * d2 * yv1);
    float r3 = w0 * x0 * y2 + w2 * S2f * (p0 * yv1 - p1 * y0)
             + w4 * (CUf * (d0 * y0 + d4 * y2 + d3 * yv1) - CVf * d2 * y2);
    float r4 = w3 * S2f * (p0 * y2 + p2 * y0)
             + w5 * (CAf * (d3 * y2 - d1 * y0) - 2.f * CAf * d4 * yv1);
    float r5 = w3 * S2f * (p0 * yv1 + p1 * y0)
             + w5 * (CAf * (d0 * y0 - d3 * yv1 + d4 * y2) + S2f * d2 * y2);
    float r6 = w3 * (CA2f * p1 * yv1 - CAf * (p0 * y0 + p2 * y2))
             + w5 * S2f * (d3 * y0 - d1 * y2);
    float r7 = w3 * S2f * (p1 * y2 + p2 * yv1)
             + w5 * (CAf * (d1 * yv1 - d0 * y2 + d4 * y0) - S2f * d2 * y0);
    float r8 = w3 * S2f * (p2 * y2 - p0 * y0)
             + w5 * CAf * (2.f * d0 * yv1 - d1 * y2 - d3 * y0);

    float q0 = w1 * S3f * (A1[1][ch] + A2[2][ch] + A3[3][ch]);
    float q1 = w0 * A1[0][ch] + w2 * S2f * (A3[2][ch] - A2[3][ch])
             + w4 * (CUf * (A3[4][ch] + A2[5][ch] - A1[8][ch]) - CVf * A1[6][ch]);
    float q2 = w0 * A2[0][ch] + w2 * S2f * (A1[3][ch] - A3[1][ch])
             + w4 * (CUf * (A1[5][ch] + A3[7][ch]) + CWf * A2[6][ch]);
    float q3 = w0 * A3[0][ch] + w2 * S2f * (A2[1][ch] - A1[2][ch])
             + w4 * (CUf * (A1[4][ch] + A3[8][ch] + A2[7][ch]) - CVf * A3[6][ch]);
    float q4 = w3 * S2f * (A3[1][ch] + A1[3][ch])
             + w5 * (CAf * (A3[7][ch] - A1[5][ch]) - 2.f * CAf * A2[8][ch]);
    float q5 = w3 * S2f * (A2[1][ch] + A1[2][ch])
             + w5 * (CAf * (A1[4][ch] - A2[7][ch] + A3[8][ch]) + S2f * A3[6][ch]);
    float q6 = w3 * (CA2f * A2[2][ch] - CAf * (A1[1][ch] + A3[3][ch]))
             + w5 * S2f * (A1[7][ch] - A3[5][ch]);
    float q7 = w3 * S2f * (A3[2][ch] + A2[3][ch])
             + w5 * (CAf * (A2[5][ch] - A3[4][ch] + A1[8][ch]) - S2f * A1[6][ch]);
    float q8 = w3 * S2f * (A3[3][ch] - A1[1][ch])
             + w5 * CAf * (2.f * A2[4][ch] - A3[5][ch] - A1[7][ch]);

    OUT[0][ch] = r0 - q0; OUT[1][ch] = r1 - q1; OUT[2][ch] = r2 - q2;
    OUT[3][ch] = r3 - q3; OUT[4][ch] = r4 - q4; OUT[5][ch] = r5 - q5;
    OUT[6][ch] = r6 - q6; OUT[7][ch] = r7 - q7; OUT[8][ch] = r8 - q8;
  }

  #pragma unroll
  for (int m = 0; m < 9; ++m) {
    unsigned dw = (unsigned)f2b(OUT[m][0]) | ((unsigned)f2b(OUT[m][1]) << 16);
    *(unsigned*)(D + ((size_t)b * MTOT + m) * CH + c0) = dw;
  }
}

extern "C" void kernel_launch(void* const* d_in, const int* in_sizes, int n_in,
                              void* d_out, int out_size, void* d_ws, size_t ws_size,
                              hipStream_t stream) {
  (void)in_sizes; (void)n_in; (void)out_size; (void)ws_size;
  const float* pos     = (const float*)d_in[0];
  const float* exp_pos = (const float*)d_in[1];
  // d_in[2] = h : unused by the reference computation
  const float* exp_h   = (const float*)d_in[3];
  const float* alpha   = (const float*)d_in[4];
  const int*   idx     = (const int*)d_in[5];
  const float* w1w     = (const float*)d_in[6];
  const float* w1b     = (const float*)d_in[7];
  const float* w2w     = (const float*)d_in[8];
  const float* w2b     = (const float*)d_in[9];
  const float* tpw     = (const float*)d_in[10];
  float* out = (float*)d_out;

  unsigned short* eh1 = (unsigned short*)d_ws;                  // bf16 [4096*9*128]
  unsigned short* dif = eh1 + (size_t)NN * MTOT * CH;           // bf16 [4096*9*128]
  unsigned short* w1s = dif + (size_t)NN * MTOT * CH;           // bf16 swizzled [3*16384]
  unsigned short* w2s = w1s + 3 * 16384;                        // bf16 swizzled [3*16384]

  wprep<<<48, 256, 0, stream>>>(w1w, w2w, w1s, w2s);
  so3lin_mfma<0, 1, 0><<<576, 256, 0, stream>>>(exp_h, w1s, w1b, eh1);
  agg_tp_b<<<NN / 4, 256, 0, stream>>>(eh1, pos, exp_pos, alpha, idx, tpw, dif);
  so3lin_mfma<1, 0, 1><<<576, 256, 0, stream>>>(dif, w2s, w2b, out);
}